// Round 8
// baseline (202.040 us; speedup 1.0000x reference)
//
#include <hip/hip_runtime.h>

// CRNN fused, round 7: R6 numerics, instruction-diet.
// - full m-unroll => ds_read immediate offsets, hoisted per-lane bases
// - sW2 stride 528 (16B rows) => one b128 per (m,n) {h|l}
// - unconditional mix load (g!=0 lanes multiply zero B-slots => garbage-safe)
// - trunc+perm hi/lo splits everywhere (verified primitive from R6's P-path)
#define NSPEC 32
#define NREAC 256
#define NGRID 2048
#define S2STRIDE 528   // ushorts; 1056B rows: 16B-aligned -> b128-able

typedef __bf16 bf16x8_t __attribute__((ext_vector_type(8)));
typedef short shortx4_t __attribute__((ext_vector_type(4)));
typedef float f32x4_t  __attribute__((ext_vector_type(4)));

union F8 { ushort u[8]; uint4 q; bf16x8_t v; };
union F4 { ushort u[4]; uint2 q; shortx4_t v; };

#define LOG2E  1.4426950408889634f
#define CLAMP2 43.280851f           // 30 * log2(e)

__device__ __forceinline__ ushort f2bh(float x) {          // f32 -> bf16 bits (RNE)
    uint b = __float_as_uint(x);
    return (ushort)((b + 0x7FFFu + ((b >> 16) & 1u)) >> 16);
}
__device__ __forceinline__ float bh2f(ushort h) {
    return __uint_as_float(((uint)h) << 16);
}
__device__ __forceinline__ float med3(float x, float lo, float hi) {
    return __builtin_amdgcn_fmed3f(x, lo, hi);
}
// D = { y.hi16 : x.hi16 } (low ushort = x's top 16 bits). Verified on HW (R6).
__device__ __forceinline__ uint pack_hi16(float x, float y) {
    return __builtin_amdgcn_perm(__float_as_uint(y), __float_as_uint(x), 0x07060302u);
}
__device__ __forceinline__ float trunc_hi(float x) {
    return __uint_as_float(__float_as_uint(x) & 0xffff0000u);
}

__global__ __launch_bounds__(512, 4) void crnn_mfma(
    const float* __restrict__ u,       // [B,32]
    const float* __restrict__ t,       // [B]
    const float* __restrict__ tsteps,  // [2048]
    const float* __restrict__ T_tab,   // [2048]
    const float* __restrict__ w_in,    // [34,256]
    const float* __restrict__ w_b,     // [256]
    const float* __restrict__ w_out,   // [32,256]
    float* __restrict__ out,           // [B,32]
    int iters)
{
    // sW1 row r: 4 chunks of [8 hi | 8 lo] for k=0..31, then
    // mix(8) = {h32s,h33,h32s,h33,l32s,l33,hb,lb}; w32,w_b pre-scaled by log2e.
    __shared__ ushort sW1[256][72];        // 36 KB
    __shared__ ushort sW2[32][S2STRIDE];   // 33 KB; per m,n: [4 hi | 4 lo] = 16B

    const int tid = threadIdx.x;

    // ---- stage weights (RNE splits, once per block) ----
    if (tid < 256) {
        const int r = tid;
        #pragma unroll
        for (int k = 0; k < 32; ++k) {
            float f = w_in[k * NREAC + r];           // unscaled: pairs with log2(Y)
            ushort h = f2bh(f), l = f2bh(f - bh2f(h));
            sW1[r][(k >> 3) * 16 + (k & 7)]     = h;
            sW1[r][(k >> 3) * 16 + (k & 7) + 8] = l;
        }
        float f32v = w_in[32 * NREAC + r] * LOG2E;   // pairs with -1/(R*T)
        float f33v = w_in[33 * NREAC + r];           // pairs with log2(T)
        float fbv  = w_b[r] * LOG2E;
        ushort h32 = f2bh(f32v), l32 = f2bh(f32v - bh2f(h32));
        ushort h33 = f2bh(f33v), l33 = f2bh(f33v - bh2f(h33));
        ushort hb  = f2bh(fbv),  lb  = f2bh(fbv  - bh2f(hb));
        sW1[r][64] = h32; sW1[r][65] = h33; sW1[r][66] = h32; sW1[r][67] = h33;
        sW1[r][68] = l32; sW1[r][69] = l33; sW1[r][70] = hb;  sW1[r][71] = lb;
    } else {
        const int tt2 = tid - 256;
        const int s2 = tt2 >> 3;
        const int kb = (tt2 & 7) * 32;
        for (int k = kb; k < kb + 32; ++k) {
            float f = w_out[s2 * NREAC + k];
            ushort h = f2bh(f), l = f2bh(f - bh2f(h));
            sW2[s2][(k >> 2) * 8 + (k & 3)]     = h;
            sW2[s2][(k >> 2) * 8 + (k & 3) + 4] = l;
        }
    }
    __syncthreads();   // weights read-only afterwards: no barriers in main loop

    const int wid  = tid >> 6;            // 0..7
    const int lane = tid & 63;
    const int g    = lane >> 4;           // 0..3
    const int c    = lane & 15;           // 0..15

    // loop-invariant per-lane LDS bases (ds_read gets immediate per-m offsets)
    const ushort* w1base = &sW1[c][0];            // + m*1152 ushorts per m-tile
    const ushort* w2base0 = &sW2[c][8 * g];       // n=0 row, + m*32 per m
    const ushort* w2base1 = &sW2[16 + c][8 * g];  // n=1 row

    const long long wbase = ((long long)blockIdx.x * 8 + wid) * (32LL * iters);

    #pragma unroll 1
    for (int it = 0; it < iters; ++it) {
        const long long base = wbase + (long long)it * 32;

        // ---- Phase A: w_v fragments (log2 domain, trunc+perm splits) ----
        F8 vh[2], vl[2], mx[2];
        #pragma unroll
        for (int grp = 0; grp < 2; ++grp) {
            const long long s = base + grp * 16 + c;
            const float* up = u + s * NSPEC + g * 8;
            float4 ua = *(const float4*)up;
            float4 ub = *(const float4*)(up + 4);
            float x2[8];
            x2[0] = __builtin_amdgcn_logf(med3(ua.x, 1e-5f, 60.0f));
            x2[1] = __builtin_amdgcn_logf(med3(ua.y, 1e-5f, 60.0f));
            x2[2] = __builtin_amdgcn_logf(med3(ua.z, 1e-5f, 60.0f));
            x2[3] = __builtin_amdgcn_logf(med3(ua.w, 1e-5f, 60.0f));
            x2[4] = __builtin_amdgcn_logf(med3(ub.x, 1e-5f, 60.0f));
            x2[5] = __builtin_amdgcn_logf(med3(ub.y, 1e-5f, 60.0f));
            x2[6] = __builtin_amdgcn_logf(med3(ub.z, 1e-5f, 60.0f));
            x2[7] = __builtin_amdgcn_logf(med3(ub.w, 1e-5f, 60.0f));
            vh[grp].q = make_uint4(pack_hi16(x2[0], x2[1]), pack_hi16(x2[2], x2[3]),
                                   pack_hi16(x2[4], x2[5]), pack_hi16(x2[6], x2[7]));
            float y0 = x2[0] - trunc_hi(x2[0]), y1 = x2[1] - trunc_hi(x2[1]);
            float y2 = x2[2] - trunc_hi(x2[2]), y3 = x2[3] - trunc_hi(x2[3]);
            float y4 = x2[4] - trunc_hi(x2[4]), y5 = x2[5] - trunc_hi(x2[5]);
            float y6 = x2[6] - trunc_hi(x2[6]), y7 = x2[7] - trunc_hi(x2[7]);
            vl[grp].q = make_uint4(pack_hi16(y0, y1), pack_hi16(y2, y3),
                                   pack_hi16(y4, y5), pack_hi16(y6, y7));

            // jnp.interp clone (uniform-grid guess + exact micro-adjust)
            float tt = t[s];
            int i0 = (int)(tt * 2047.0f);
            i0 = i0 < 0 ? 0 : (i0 > 2046 ? 2046 : i0);
            while (i0 < 2046 && tt >= tsteps[i0 + 1]) ++i0;
            while (i0 > 0 && tt < tsteps[i0]) --i0;
            float x0 = tsteps[i0], x1 = tsteps[i0 + 1];
            float T = T_tab[i0] + (tt - x0) / (x1 - x0) * (T_tab[i0 + 1] - T_tab[i0]);
            float sp0 = -1.0f / (0.0019872036f * T);     // pairs with w32*log2e
            float sp1 = __builtin_amdgcn_logf(T);        // log2(T), pairs with w33
            uint pkh = pack_hi16(sp0, sp1);
            uint pkl = pack_hi16(sp0 - trunc_hi(sp0), sp1 - trunc_hi(sp1));
            if (g == 0) mx[grp].q = make_uint4(pkh, pkl, pkh, 0x3F803F80u);
            else        mx[grp].q = make_uint4(0u, 0u, 0u, 0u);
        }

        // ---- fused GEMM1 -> exp2 -> GEMM2, fully unrolled m ----
        f32x4_t acc2[2][2];
        #pragma unroll
        for (int grp = 0; grp < 2; ++grp)
            #pragma unroll
            for (int n = 0; n < 2; ++n)
                acc2[grp][n] = (f32x4_t){0.f, 0.f, 0.f, 0.f};

        #pragma unroll
        for (int m = 0; m < 16; ++m) {
            const ushort* r1 = w1base + m * (16 * 72);
            bf16x8_t Wh = __builtin_bit_cast(bf16x8_t, *(const uint4*)(r1 + 16 * g));
            bf16x8_t Wl = __builtin_bit_cast(bf16x8_t, *(const uint4*)(r1 + 16 * g + 8));
            // unconditional: g!=0 lanes' B-slots are zero, so their A values are don't-care
            bf16x8_t Wm = __builtin_bit_cast(bf16x8_t, *(const uint4*)(r1 + 64));

            uint4 hl0 = *(const uint4*)(w2base0 + m * 32);   // {h01,h23,l01,l23} n=0
            uint4 hl1 = *(const uint4*)(w2base1 + m * 32);   // n=1
            F4 W2h[2], W2l[2];
            W2h[0].q = make_uint2(hl0.x, hl0.y); W2l[0].q = make_uint2(hl0.z, hl0.w);
            W2h[1].q = make_uint2(hl1.x, hl1.y); W2l[1].q = make_uint2(hl1.z, hl1.w);

            #pragma unroll
            for (int grp = 0; grp < 2; ++grp) {
                f32x4_t a = (f32x4_t){0.f, 0.f, 0.f, 0.f};
                a = __builtin_amdgcn_mfma_f32_16x16x32_bf16(Wh, vh[grp].v, a, 0, 0, 0);
                a = __builtin_amdgcn_mfma_f32_16x16x32_bf16(Wh, vl[grp].v, a, 0, 0, 0);
                a = __builtin_amdgcn_mfma_f32_16x16x32_bf16(Wl, vh[grp].v, a, 0, 0, 0);
                a = __builtin_amdgcn_mfma_f32_16x16x32_bf16(Wm, mx[grp].v, a, 0, 0, 0);

                float e0 = __builtin_amdgcn_exp2f(med3(a[0], -CLAMP2, CLAMP2));
                float e1 = __builtin_amdgcn_exp2f(med3(a[1], -CLAMP2, CLAMP2));
                float e2 = __builtin_amdgcn_exp2f(med3(a[2], -CLAMP2, CLAMP2));
                float e3 = __builtin_amdgcn_exp2f(med3(a[3], -CLAMP2, CLAMP2));
                F4 ph, pl;
                ph.q = make_uint2(pack_hi16(e0, e1), pack_hi16(e2, e3));
                float l0 = e0 - trunc_hi(e0), l1 = e1 - trunc_hi(e1);
                float l2 = e2 - trunc_hi(e2), l3 = e3 - trunc_hi(e3);
                pl.q = make_uint2(pack_hi16(l0, l1), pack_hi16(l2, l3));

                #pragma unroll
                for (int n = 0; n < 2; ++n) {
                    acc2[grp][n] = __builtin_amdgcn_mfma_f32_16x16x16bf16_1k(W2h[n].v, ph.v, acc2[grp][n], 0, 0, 0);
                    acc2[grp][n] = __builtin_amdgcn_mfma_f32_16x16x16bf16_1k(W2h[n].v, pl.v, acc2[grp][n], 0, 0, 0);
                    acc2[grp][n] = __builtin_amdgcn_mfma_f32_16x16x16bf16_1k(W2l[n].v, ph.v, acc2[grp][n], 0, 0, 0);
                }
            }
        }

        // ---- epilogue: clip + store ----
        #pragma unroll
        for (int grp = 0; grp < 2; ++grp) {
            const long long s = base + grp * 16 + c;
            float* op = out + s * NSPEC + 4 * g;
            #pragma unroll
            for (int n = 0; n < 2; ++n) {
                f32x4_t o = acc2[grp][n];
                float4 st;
                st.x = med3(o[0], -1e4f, 1e4f);
                st.y = med3(o[1], -1e4f, 1e4f);
                st.z = med3(o[2], -1e4f, 1e4f);
                st.w = med3(o[3], -1e4f, 1e4f);
                *(float4*)(op + 16 * n) = st;
            }
        }
    }
}

extern "C" void kernel_launch(void* const* d_in, const int* in_sizes, int n_in,
                              void* d_out, int out_size, void* d_ws, size_t ws_size,
                              hipStream_t stream) {
    const float* u      = (const float*)d_in[0];
    const float* t      = (const float*)d_in[1];
    const float* tsteps = (const float*)d_in[2];
    const float* T_tab  = (const float*)d_in[3];
    // d_in[4] = P_tab : unused in the reference
    const float* w_in   = (const float*)d_in[5];
    const float* w_b    = (const float*)d_in[6];
    const float* w_out  = (const float*)d_in[7];
    float* out = (float*)d_out;

    const int B = in_sizes[0] / NSPEC;           // 262144
    const int ITERS = 2;
    const int spb = 8 * 32 * ITERS;              // 512 samples per block (8 waves)
    const int grid = B / spb;                    // 512 blocks -> 2 per CU
    crnn_mfma<<<grid, 512, 0, stream>>>(u, t, tsteps, T_tab, w_in, w_b, w_out, out, ITERS);
}

// Round 9
// 43.277 us; speedup vs baseline: 4.6685x; 4.6685x over previous
//
#include <hip/hip_runtime.h>

// CRNN fused, round 8: R7's instruction diet with R6's proven unroll factor.
// R7 post-mortem: full m-unroll caused ~290MB/way scratch spill under the
// 128-VGPR launch-bounds cap. Diet items (b128 sW2, unconditional mix,
// trunc+perm splits) are numerically verified (absmax 4.0) and kept.
#define NSPEC 32
#define NREAC 256
#define NGRID 2048
#define S2STRIDE 528   // ushorts; 1056B rows: 16B-aligned -> b128 per (m,n)

typedef __bf16 bf16x8_t __attribute__((ext_vector_type(8)));
typedef short shortx4_t __attribute__((ext_vector_type(4)));
typedef float f32x4_t  __attribute__((ext_vector_type(4)));

union F8 { ushort u[8]; uint4 q; bf16x8_t v; };
union F4 { ushort u[4]; uint2 q; shortx4_t v; };

#define LOG2E  1.4426950408889634f
#define CLAMP2 43.280851f           // 30 * log2(e)

__device__ __forceinline__ ushort f2bh(float x) {          // f32 -> bf16 bits (RNE)
    uint b = __float_as_uint(x);
    return (ushort)((b + 0x7FFFu + ((b >> 16) & 1u)) >> 16);
}
__device__ __forceinline__ float bh2f(ushort h) {
    return __uint_as_float(((uint)h) << 16);
}
__device__ __forceinline__ float med3(float x, float lo, float hi) {
    return __builtin_amdgcn_fmed3f(x, lo, hi);
}
// D = { y.hi16 : x.hi16 } (low ushort = x's top 16 bits). HW-verified (R6/R7).
__device__ __forceinline__ uint pack_hi16(float x, float y) {
    return __builtin_amdgcn_perm(__float_as_uint(y), __float_as_uint(x), 0x07060302u);
}
__device__ __forceinline__ float trunc_hi(float x) {
    return __uint_as_float(__float_as_uint(x) & 0xffff0000u);
}

__global__ __launch_bounds__(512, 4) void crnn_mfma(
    const float* __restrict__ u,       // [B,32]
    const float* __restrict__ t,       // [B]
    const float* __restrict__ tsteps,  // [2048]
    const float* __restrict__ T_tab,   // [2048]
    const float* __restrict__ w_in,    // [34,256]
    const float* __restrict__ w_b,     // [256]
    const float* __restrict__ w_out,   // [32,256]
    float* __restrict__ out,           // [B,32]
    int iters)
{
    // sW1 row r: 4 chunks of [8 hi | 8 lo] for k=0..31, then
    // mix(8) = {h32s,h33,h32s,h33,l32s,l33,hb,lb}; w32,w_b pre-scaled by log2e.
    __shared__ ushort sW1[256][72];        // 36 KB
    __shared__ ushort sW2[32][S2STRIDE];   // 33 KB; per (m,n): [4 hi | 4 lo] = 16B

    const int tid = threadIdx.x;

    // ---- stage weights (RNE splits, once per block) ----
    if (tid < 256) {
        const int r = tid;
        #pragma unroll
        for (int k = 0; k < 32; ++k) {
            float f = w_in[k * NREAC + r];           // unscaled: pairs with log2(Y)
            ushort h = f2bh(f), l = f2bh(f - bh2f(h));
            sW1[r][(k >> 3) * 16 + (k & 7)]     = h;
            sW1[r][(k >> 3) * 16 + (k & 7) + 8] = l;
        }
        float f32v = w_in[32 * NREAC + r] * LOG2E;   // pairs with -1/(R*T)
        float f33v = w_in[33 * NREAC + r];           // pairs with log2(T)
        float fbv  = w_b[r] * LOG2E;
        ushort h32 = f2bh(f32v), l32 = f2bh(f32v - bh2f(h32));
        ushort h33 = f2bh(f33v), l33 = f2bh(f33v - bh2f(h33));
        ushort hb  = f2bh(fbv),  lb  = f2bh(fbv  - bh2f(hb));
        sW1[r][64] = h32; sW1[r][65] = h33; sW1[r][66] = h32; sW1[r][67] = h33;
        sW1[r][68] = l32; sW1[r][69] = l33; sW1[r][70] = hb;  sW1[r][71] = lb;
    } else {
        const int tt2 = tid - 256;
        const int s2 = tt2 >> 3;
        const int kb = (tt2 & 7) * 32;
        for (int k = kb; k < kb + 32; ++k) {
            float f = w_out[s2 * NREAC + k];
            ushort h = f2bh(f), l = f2bh(f - bh2f(h));
            sW2[s2][(k >> 2) * 8 + (k & 3)]     = h;
            sW2[s2][(k >> 2) * 8 + (k & 3) + 4] = l;
        }
    }
    __syncthreads();   // weights read-only afterwards: no barriers in main loop

    const int wid  = tid >> 6;            // 0..7
    const int lane = tid & 63;
    const int g    = lane >> 4;           // 0..3
    const int c    = lane & 15;           // 0..15

    // loop-invariant per-lane LDS bases
    const ushort* w1base  = &sW1[c][0];            // + m*(16*72) per m-tile
    const ushort* w2base0 = &sW2[c][8 * g];        // n=0 row, + m*32 per m
    const ushort* w2base1 = &sW2[16 + c][8 * g];   // n=1 row

    const long long wbase = ((long long)blockIdx.x * 8 + wid) * (32LL * iters);

    #pragma unroll 1
    for (int it = 0; it < iters; ++it) {
        const long long base = wbase + (long long)it * 32;

        // ---- Phase A: w_v fragments (log2 domain, trunc+perm splits) ----
        F8 vh[2], vl[2], mx[2];
        #pragma unroll
        for (int grp = 0; grp < 2; ++grp) {
            const long long s = base + grp * 16 + c;
            const float* up = u + s * NSPEC + g * 8;
            float4 ua = *(const float4*)up;
            float4 ub = *(const float4*)(up + 4);
            float x2[8];
            x2[0] = __builtin_amdgcn_logf(med3(ua.x, 1e-5f, 60.0f));
            x2[1] = __builtin_amdgcn_logf(med3(ua.y, 1e-5f, 60.0f));
            x2[2] = __builtin_amdgcn_logf(med3(ua.z, 1e-5f, 60.0f));
            x2[3] = __builtin_amdgcn_logf(med3(ua.w, 1e-5f, 60.0f));
            x2[4] = __builtin_amdgcn_logf(med3(ub.x, 1e-5f, 60.0f));
            x2[5] = __builtin_amdgcn_logf(med3(ub.y, 1e-5f, 60.0f));
            x2[6] = __builtin_amdgcn_logf(med3(ub.z, 1e-5f, 60.0f));
            x2[7] = __builtin_amdgcn_logf(med3(ub.w, 1e-5f, 60.0f));
            vh[grp].q = make_uint4(pack_hi16(x2[0], x2[1]), pack_hi16(x2[2], x2[3]),
                                   pack_hi16(x2[4], x2[5]), pack_hi16(x2[6], x2[7]));
            float y0 = x2[0] - trunc_hi(x2[0]), y1 = x2[1] - trunc_hi(x2[1]);
            float y2 = x2[2] - trunc_hi(x2[2]), y3 = x2[3] - trunc_hi(x2[3]);
            float y4 = x2[4] - trunc_hi(x2[4]), y5 = x2[5] - trunc_hi(x2[5]);
            float y6 = x2[6] - trunc_hi(x2[6]), y7 = x2[7] - trunc_hi(x2[7]);
            vl[grp].q = make_uint4(pack_hi16(y0, y1), pack_hi16(y2, y3),
                                   pack_hi16(y4, y5), pack_hi16(y6, y7));

            // jnp.interp clone (uniform-grid guess + exact micro-adjust)
            float tt = t[s];
            int i0 = (int)(tt * 2047.0f);
            i0 = i0 < 0 ? 0 : (i0 > 2046 ? 2046 : i0);
            while (i0 < 2046 && tt >= tsteps[i0 + 1]) ++i0;
            while (i0 > 0 && tt < tsteps[i0]) --i0;
            float x0 = tsteps[i0], x1 = tsteps[i0 + 1];
            float T = T_tab[i0] + (tt - x0) / (x1 - x0) * (T_tab[i0 + 1] - T_tab[i0]);
            float sp0 = -1.0f / (0.0019872036f * T);     // pairs with w32*log2e
            float sp1 = __builtin_amdgcn_logf(T);        // log2(T), pairs with w33
            uint pkh = pack_hi16(sp0, sp1);
            uint pkl = pack_hi16(sp0 - trunc_hi(sp0), sp1 - trunc_hi(sp1));
            if (g == 0) mx[grp].q = make_uint4(pkh, pkl, pkh, 0x3F803F80u);
            else        mx[grp].q = make_uint4(0u, 0u, 0u, 0u);
        }

        // ---- fused GEMM1 -> exp2 -> GEMM2, m unrolled x4 (R6-proven) ----
        f32x4_t acc2[2][2];
        #pragma unroll
        for (int grp = 0; grp < 2; ++grp)
            #pragma unroll
            for (int n = 0; n < 2; ++n)
                acc2[grp][n] = (f32x4_t){0.f, 0.f, 0.f, 0.f};

        #pragma unroll 4
        for (int m = 0; m < 16; ++m) {
            const ushort* r1 = w1base + m * (16 * 72);
            bf16x8_t Wh = __builtin_bit_cast(bf16x8_t, *(const uint4*)(r1 + 16 * g));
            bf16x8_t Wl = __builtin_bit_cast(bf16x8_t, *(const uint4*)(r1 + 16 * g + 8));
            // unconditional: g!=0 lanes' mx B-rows are zero -> A garbage is harmless
            bf16x8_t Wm = __builtin_bit_cast(bf16x8_t, *(const uint4*)(r1 + 64));

            uint4 hl0 = *(const uint4*)(w2base0 + m * 32);   // {h01,h23,l01,l23} n=0
            uint4 hl1 = *(const uint4*)(w2base1 + m * 32);   // n=1
            F4 W2h[2], W2l[2];
            W2h[0].q = make_uint2(hl0.x, hl0.y); W2l[0].q = make_uint2(hl0.z, hl0.w);
            W2h[1].q = make_uint2(hl1.x, hl1.y); W2l[1].q = make_uint2(hl1.z, hl1.w);

            #pragma unroll
            for (int grp = 0; grp < 2; ++grp) {
                f32x4_t a = (f32x4_t){0.f, 0.f, 0.f, 0.f};
                a = __builtin_amdgcn_mfma_f32_16x16x32_bf16(Wh, vh[grp].v, a, 0, 0, 0);
                a = __builtin_amdgcn_mfma_f32_16x16x32_bf16(Wh, vl[grp].v, a, 0, 0, 0);
                a = __builtin_amdgcn_mfma_f32_16x16x32_bf16(Wl, vh[grp].v, a, 0, 0, 0);
                a = __builtin_amdgcn_mfma_f32_16x16x32_bf16(Wm, mx[grp].v, a, 0, 0, 0);

                float e0 = __builtin_amdgcn_exp2f(med3(a[0], -CLAMP2, CLAMP2));
                float e1 = __builtin_amdgcn_exp2f(med3(a[1], -CLAMP2, CLAMP2));
                float e2 = __builtin_amdgcn_exp2f(med3(a[2], -CLAMP2, CLAMP2));
                float e3 = __builtin_amdgcn_exp2f(med3(a[3], -CLAMP2, CLAMP2));
                F4 ph, pl;
                ph.q = make_uint2(pack_hi16(e0, e1), pack_hi16(e2, e3));
                float l0 = e0 - trunc_hi(e0), l1 = e1 - trunc_hi(e1);
                float l2 = e2 - trunc_hi(e2), l3 = e3 - trunc_hi(e3);
                pl.q = make_uint2(pack_hi16(l0, l1), pack_hi16(l2, l3));

                #pragma unroll
                for (int n = 0; n < 2; ++n) {
                    acc2[grp][n] = __builtin_amdgcn_mfma_f32_16x16x16bf16_1k(W2h[n].v, ph.v, acc2[grp][n], 0, 0, 0);
                    acc2[grp][n] = __builtin_amdgcn_mfma_f32_16x16x16bf16_1k(W2h[n].v, pl.v, acc2[grp][n], 0, 0, 0);
                    acc2[grp][n] = __builtin_amdgcn_mfma_f32_16x16x16bf16_1k(W2l[n].v, ph.v, acc2[grp][n], 0, 0, 0);
                }
            }
        }

        // ---- epilogue: clip + store ----
        #pragma unroll
        for (int grp = 0; grp < 2; ++grp) {
            const long long s = base + grp * 16 + c;
            float* op = out + s * NSPEC + 4 * g;
            #pragma unroll
            for (int n = 0; n < 2; ++n) {
                f32x4_t o = acc2[grp][n];
                float4 st;
                st.x = med3(o[0], -1e4f, 1e4f);
                st.y = med3(o[1], -1e4f, 1e4f);
                st.z = med3(o[2], -1e4f, 1e4f);
                st.w = med3(o[3], -1e4f, 1e4f);
                *(float4*)(op + 16 * n) = st;
            }
        }
    }
}

extern "C" void kernel_launch(void* const* d_in, const int* in_sizes, int n_in,
                              void* d_out, int out_size, void* d_ws, size_t ws_size,
                              hipStream_t stream) {
    const float* u      = (const float*)d_in[0];
    const float* t      = (const float*)d_in[1];
    const float* tsteps = (const float*)d_in[2];
    const float* T_tab  = (const float*)d_in[3];
    // d_in[4] = P_tab : unused in the reference
    const float* w_in   = (const float*)d_in[5];
    const float* w_b    = (const float*)d_in[6];
    const float* w_out  = (const float*)d_in[7];
    float* out = (float*)d_out;

    const int B = in_sizes[0] / NSPEC;           // 262144
    const int ITERS = 2;
    const int spb = 8 * 32 * ITERS;              // 512 samples per block (8 waves)
    const int grid = B / spb;                    // 512 blocks -> 2 per CU
    crnn_mfma<<<grid, 512, 0, stream>>>(u, t, tsteps, T_tab, w_in, w_b, w_out, out, ITERS);
}

// Round 10
// 42.685 us; speedup vs baseline: 4.7333x; 1.0139x over previous
//
#include <hip/hip_runtime.h>

// CRNN fused, round 8: R7's instruction diet with R6's proven unroll factor.
// R7 post-mortem: full m-unroll caused ~290MB/way scratch spill under the
// 128-VGPR launch-bounds cap. Diet items (b128 sW2, unconditional mix,
// trunc+perm splits) are numerically verified (absmax 4.0) and kept.
#define NSPEC 32
#define NREAC 256
#define NGRID 2048
#define S2STRIDE 528   // ushorts; 1056B rows: 16B-aligned -> b128 per (m,n)

typedef __bf16 bf16x8_t __attribute__((ext_vector_type(8)));
typedef short shortx4_t __attribute__((ext_vector_type(4)));
typedef float f32x4_t  __attribute__((ext_vector_type(4)));

union F8 { ushort u[8]; uint4 q; bf16x8_t v; };
union F4 { ushort u[4]; uint2 q; shortx4_t v; };

#define LOG2E  1.4426950408889634f
#define CLAMP2 43.280851f           // 30 * log2(e)

__device__ __forceinline__ ushort f2bh(float x) {          // f32 -> bf16 bits (RNE)
    uint b = __float_as_uint(x);
    return (ushort)((b + 0x7FFFu + ((b >> 16) & 1u)) >> 16);
}
__device__ __forceinline__ float bh2f(ushort h) {
    return __uint_as_float(((uint)h) << 16);
}
__device__ __forceinline__ float med3(float x, float lo, float hi) {
    return __builtin_amdgcn_fmed3f(x, lo, hi);
}
// D = { y.hi16 : x.hi16 } (low ushort = x's top 16 bits). HW-verified (R6/R7).
__device__ __forceinline__ uint pack_hi16(float x, float y) {
    return __builtin_amdgcn_perm(__float_as_uint(y), __float_as_uint(x), 0x07060302u);
}
__device__ __forceinline__ float trunc_hi(float x) {
    return __uint_as_float(__float_as_uint(x) & 0xffff0000u);
}

__global__ __launch_bounds__(512, 4) void crnn_mfma(
    const float* __restrict__ u,       // [B,32]
    const float* __restrict__ t,       // [B]
    const float* __restrict__ tsteps,  // [2048]
    const float* __restrict__ T_tab,   // [2048]
    const float* __restrict__ w_in,    // [34,256]
    const float* __restrict__ w_b,     // [256]
    const float* __restrict__ w_out,   // [32,256]
    float* __restrict__ out,           // [B,32]
    int iters)
{
    // sW1 row r: 4 chunks of [8 hi | 8 lo] for k=0..31, then
    // mix(8) = {h32s,h33,h32s,h33,l32s,l33,hb,lb}; w32,w_b pre-scaled by log2e.
    __shared__ ushort sW1[256][72];        // 36 KB
    __shared__ ushort sW2[32][S2STRIDE];   // 33 KB; per (m,n): [4 hi | 4 lo] = 16B

    const int tid = threadIdx.x;

    // ---- stage weights (RNE splits, once per block) ----
    if (tid < 256) {
        const int r = tid;
        #pragma unroll
        for (int k = 0; k < 32; ++k) {
            float f = w_in[k * NREAC + r];           // unscaled: pairs with log2(Y)
            ushort h = f2bh(f), l = f2bh(f - bh2f(h));
            sW1[r][(k >> 3) * 16 + (k & 7)]     = h;
            sW1[r][(k >> 3) * 16 + (k & 7) + 8] = l;
        }
        float f32v = w_in[32 * NREAC + r] * LOG2E;   // pairs with -1/(R*T)
        float f33v = w_in[33 * NREAC + r];           // pairs with log2(T)
        float fbv  = w_b[r] * LOG2E;
        ushort h32 = f2bh(f32v), l32 = f2bh(f32v - bh2f(h32));
        ushort h33 = f2bh(f33v), l33 = f2bh(f33v - bh2f(h33));
        ushort hb  = f2bh(fbv),  lb  = f2bh(fbv  - bh2f(hb));
        sW1[r][64] = h32; sW1[r][65] = h33; sW1[r][66] = h32; sW1[r][67] = h33;
        sW1[r][68] = l32; sW1[r][69] = l33; sW1[r][70] = hb;  sW1[r][71] = lb;
    } else {
        const int tt2 = tid - 256;
        const int s2 = tt2 >> 3;
        const int kb = (tt2 & 7) * 32;
        for (int k = kb; k < kb + 32; ++k) {
            float f = w_out[s2 * NREAC + k];
            ushort h = f2bh(f), l = f2bh(f - bh2f(h));
            sW2[s2][(k >> 2) * 8 + (k & 3)]     = h;
            sW2[s2][(k >> 2) * 8 + (k & 3) + 4] = l;
        }
    }
    __syncthreads();   // weights read-only afterwards: no barriers in main loop

    const int wid  = tid >> 6;            // 0..7
    const int lane = tid & 63;
    const int g    = lane >> 4;           // 0..3
    const int c    = lane & 15;           // 0..15

    // loop-invariant per-lane LDS bases
    const ushort* w1base  = &sW1[c][0];            // + m*(16*72) per m-tile
    const ushort* w2base0 = &sW2[c][8 * g];        // n=0 row, + m*32 per m
    const ushort* w2base1 = &sW2[16 + c][8 * g];   // n=1 row

    const long long wbase = ((long long)blockIdx.x * 8 + wid) * (32LL * iters);

    #pragma unroll 1
    for (int it = 0; it < iters; ++it) {
        const long long base = wbase + (long long)it * 32;

        // ---- Phase A: w_v fragments (log2 domain, trunc+perm splits) ----
        F8 vh[2], vl[2], mx[2];
        #pragma unroll
        for (int grp = 0; grp < 2; ++grp) {
            const long long s = base + grp * 16 + c;
            const float* up = u + s * NSPEC + g * 8;
            float4 ua = *(const float4*)up;
            float4 ub = *(const float4*)(up + 4);
            float x2[8];
            x2[0] = __builtin_amdgcn_logf(med3(ua.x, 1e-5f, 60.0f));
            x2[1] = __builtin_amdgcn_logf(med3(ua.y, 1e-5f, 60.0f));
            x2[2] = __builtin_amdgcn_logf(med3(ua.z, 1e-5f, 60.0f));
            x2[3] = __builtin_amdgcn_logf(med3(ua.w, 1e-5f, 60.0f));
            x2[4] = __builtin_amdgcn_logf(med3(ub.x, 1e-5f, 60.0f));
            x2[5] = __builtin_amdgcn_logf(med3(ub.y, 1e-5f, 60.0f));
            x2[6] = __builtin_amdgcn_logf(med3(ub.z, 1e-5f, 60.0f));
            x2[7] = __builtin_amdgcn_logf(med3(ub.w, 1e-5f, 60.0f));
            vh[grp].q = make_uint4(pack_hi16(x2[0], x2[1]), pack_hi16(x2[2], x2[3]),
                                   pack_hi16(x2[4], x2[5]), pack_hi16(x2[6], x2[7]));
            float y0 = x2[0] - trunc_hi(x2[0]), y1 = x2[1] - trunc_hi(x2[1]);
            float y2 = x2[2] - trunc_hi(x2[2]), y3 = x2[3] - trunc_hi(x2[3]);
            float y4 = x2[4] - trunc_hi(x2[4]), y5 = x2[5] - trunc_hi(x2[5]);
            float y6 = x2[6] - trunc_hi(x2[6]), y7 = x2[7] - trunc_hi(x2[7]);
            vl[grp].q = make_uint4(pack_hi16(y0, y1), pack_hi16(y2, y3),
                                   pack_hi16(y4, y5), pack_hi16(y6, y7));

            // jnp.interp clone (uniform-grid guess + exact micro-adjust)
            float tt = t[s];
            int i0 = (int)(tt * 2047.0f);
            i0 = i0 < 0 ? 0 : (i0 > 2046 ? 2046 : i0);
            while (i0 < 2046 && tt >= tsteps[i0 + 1]) ++i0;
            while (i0 > 0 && tt < tsteps[i0]) --i0;
            float x0 = tsteps[i0], x1 = tsteps[i0 + 1];
            float T = T_tab[i0] + (tt - x0) / (x1 - x0) * (T_tab[i0 + 1] - T_tab[i0]);
            float sp0 = -1.0f / (0.0019872036f * T);     // pairs with w32*log2e
            float sp1 = __builtin_amdgcn_logf(T);        // log2(T), pairs with w33
            uint pkh = pack_hi16(sp0, sp1);
            uint pkl = pack_hi16(sp0 - trunc_hi(sp0), sp1 - trunc_hi(sp1));
            if (g == 0) mx[grp].q = make_uint4(pkh, pkl, pkh, 0x3F803F80u);
            else        mx[grp].q = make_uint4(0u, 0u, 0u, 0u);
        }

        // ---- fused GEMM1 -> exp2 -> GEMM2, m unrolled x4 (R6-proven) ----
        f32x4_t acc2[2][2];
        #pragma unroll
        for (int grp = 0; grp < 2; ++grp)
            #pragma unroll
            for (int n = 0; n < 2; ++n)
                acc2[grp][n] = (f32x4_t){0.f, 0.f, 0.f, 0.f};

        #pragma unroll 4
        for (int m = 0; m < 16; ++m) {
            const ushort* r1 = w1base + m * (16 * 72);
            bf16x8_t Wh = __builtin_bit_cast(bf16x8_t, *(const uint4*)(r1 + 16 * g));
            bf16x8_t Wl = __builtin_bit_cast(bf16x8_t, *(const uint4*)(r1 + 16 * g + 8));
            // unconditional: g!=0 lanes' mx B-rows are zero -> A garbage is harmless
            bf16x8_t Wm = __builtin_bit_cast(bf16x8_t, *(const uint4*)(r1 + 64));

            uint4 hl0 = *(const uint4*)(w2base0 + m * 32);   // {h01,h23,l01,l23} n=0
            uint4 hl1 = *(const uint4*)(w2base1 + m * 32);   // n=1
            F4 W2h[2], W2l[2];
            W2h[0].q = make_uint2(hl0.x, hl0.y); W2l[0].q = make_uint2(hl0.z, hl0.w);
            W2h[1].q = make_uint2(hl1.x, hl1.y); W2l[1].q = make_uint2(hl1.z, hl1.w);

            #pragma unroll
            for (int grp = 0; grp < 2; ++grp) {
                f32x4_t a = (f32x4_t){0.f, 0.f, 0.f, 0.f};
                a = __builtin_amdgcn_mfma_f32_16x16x32_bf16(Wh, vh[grp].v, a, 0, 0, 0);
                a = __builtin_amdgcn_mfma_f32_16x16x32_bf16(Wh, vl[grp].v, a, 0, 0, 0);
                a = __builtin_amdgcn_mfma_f32_16x16x32_bf16(Wl, vh[grp].v, a, 0, 0, 0);
                a = __builtin_amdgcn_mfma_f32_16x16x32_bf16(Wm, mx[grp].v, a, 0, 0, 0);

                float e0 = __builtin_amdgcn_exp2f(med3(a[0], -CLAMP2, CLAMP2));
                float e1 = __builtin_amdgcn_exp2f(med3(a[1], -CLAMP2, CLAMP2));
                float e2 = __builtin_amdgcn_exp2f(med3(a[2], -CLAMP2, CLAMP2));
                float e3 = __builtin_amdgcn_exp2f(med3(a[3], -CLAMP2, CLAMP2));
                F4 ph, pl;
                ph.q = make_uint2(pack_hi16(e0, e1), pack_hi16(e2, e3));
                float l0 = e0 - trunc_hi(e0), l1 = e1 - trunc_hi(e1);
                float l2 = e2 - trunc_hi(e2), l3 = e3 - trunc_hi(e3);
                pl.q = make_uint2(pack_hi16(l0, l1), pack_hi16(l2, l3));

                #pragma unroll
                for (int n = 0; n < 2; ++n) {
                    acc2[grp][n] = __builtin_amdgcn_mfma_f32_16x16x16bf16_1k(W2h[n].v, ph.v, acc2[grp][n], 0, 0, 0);
                    acc2[grp][n] = __builtin_amdgcn_mfma_f32_16x16x16bf16_1k(W2h[n].v, pl.v, acc2[grp][n], 0, 0, 0);
                    acc2[grp][n] = __builtin_amdgcn_mfma_f32_16x16x16bf16_1k(W2l[n].v, ph.v, acc2[grp][n], 0, 0, 0);
                }
            }
        }

        // ---- epilogue: clip + store ----
        #pragma unroll
        for (int grp = 0; grp < 2; ++grp) {
            const long long s = base + grp * 16 + c;
            float* op = out + s * NSPEC + 4 * g;
            #pragma unroll
            for (int n = 0; n < 2; ++n) {
                f32x4_t o = acc2[grp][n];
                float4 st;
                st.x = med3(o[0], -1e4f, 1e4f);
                st.y = med3(o[1], -1e4f, 1e4f);
                st.z = med3(o[2], -1e4f, 1e4f);
                st.w = med3(o[3], -1e4f, 1e4f);
                *(float4*)(op + 16 * n) = st;
            }
        }
    }
}

extern "C" void kernel_launch(void* const* d_in, const int* in_sizes, int n_in,
                              void* d_out, int out_size, void* d_ws, size_t ws_size,
                              hipStream_t stream) {
    const float* u      = (const float*)d_in[0];
    const float* t      = (const float*)d_in[1];
    const float* tsteps = (const float*)d_in[2];
    const float* T_tab  = (const float*)d_in[3];
    // d_in[4] = P_tab : unused in the reference
    const float* w_in   = (const float*)d_in[5];
    const float* w_b    = (const float*)d_in[6];
    const float* w_out  = (const float*)d_in[7];
    float* out = (float*)d_out;

    const int B = in_sizes[0] / NSPEC;           // 262144
    const int ITERS = 2;
    const int spb = 8 * 32 * ITERS;              // 512 samples per block (8 waves)
    const int grid = B / spb;                    // 512 blocks -> 2 per CU
    crnn_mfma<<<grid, 512, 0, stream>>>(u, t, tsteps, T_tab, w_in, w_b, w_out, out, ITERS);
}